// Round 12
// baseline (509.299 us; speedup 1.0000x reference)
//
#include <hip/hip_runtime.h>
#include <math.h>

#define N 256
#define BS 32
#define NB_ 8
#define EPS 1e-5f

// One block per batch, 1024 threads (16 waves/CU). Thread (ty,tx)=(tid>>5,tid&31)
// owns an 8x8 tile of M = L^T: rows [8ty,8ty+8), cols {4tx..+3} u {128+4tx..+3}.
// vs round 7 (which passed but spilled to AGPRs at 683us): pivot inversion is
// now the round-8 wave-0 register-resident fp64 version (no Ps buffer, no
// per-k2 barriers), and all-thread paths are register-dieted (no fp64 outside
// wave 0 / colsum, epilogue reads sdiag straight from LDS) to stay under the
// 128-VGPR cap of __launch_bounds__(1024,4) with zero spill.
__global__ __launch_bounds__(1024, 4) void mtt_fused(const float* __restrict__ x,
                                                     float* __restrict__ out) {
    constexpr int LDR = N + 8;
    __shared__ alignas(16) float  Rf[BS][LDR];     // row panel / x strip  33.8KB
    __shared__ alignas(16) float  CfT[BS][LDR];    // col panel, transposed 33.8KB
    __shared__ float  Pf[BS][BS + 1];              // inverted pivot fp32   4.2KB
    __shared__ double dsum[4][N];                  // colsum partials       8KB
    __shared__ float  sdx[N];                      // exp(x[i][i])          1KB
    __shared__ float  sdiag_f[N];
    __shared__ float  sroot_f[N];
    __shared__ int    indx[BS];

    const int tid = threadIdx.x;
    const int ty = tid >> 5, tx = tid & 31;        // ty 0..31
    const int R0  = ty << 3;
    const int c0a = tx << 2;
    const int c0b = 128 + (tx << 2);
    const float* xb = x + (size_t)blockIdx.x * N * N;
    float* ob = out + (size_t)blockIdx.x * N * N;

    float m[8][8];

    // ===================== PHASE 1: build M = L^T =====================
    double csacc = 0.0;
    const int tq = tid >> 8, jc = tid & 255;
#pragma unroll 1
    for (int s = 0; s < 8; ++s) {
        {   // coalesced strip load: x rows [32s,32s+32) -> Rf
            const int rl = tid >> 5, cl = (tid & 31) << 3;
            const float* src = &xb[(size_t)(32 * s + rl) * N + cl];
            *(float4*)&Rf[rl][cl]     = *(const float4*)&src[0];
            *(float4*)&Rf[rl][cl + 4] = *(const float4*)&src[4];
        }
        __syncthreads();
#pragma unroll
        for (int r = 0; r < 8; ++r)
            csacc += (double)expf(Rf[(tq << 3) + r][jc]);
        if (tid < 32) sdx[32 * s + tid] = expf(Rf[tid][32 * s + tid]);
        if ((tx >> 3) == s) {               // first-half cols: strips 0-3
            const int jb = (tx & 7) << 2;
#pragma unroll
            for (int cc = 0; cc < 4; ++cc)
#pragma unroll
                for (int r = 0; r < 8; ++r)
                    m[r][cc] = -(expf(Rf[jb + cc][R0 + r]) + EPS);
        }
        if (s >= 4 && (tx >> 3) == s - 4) { // second-half cols: strips 4-7
            const int jb = (tx & 7) << 2;
#pragma unroll
            for (int cc = 0; cc < 4; ++cc)
#pragma unroll
                for (int r = 0; r < 8; ++r)
                    m[r][4 + cc] = -(expf(Rf[jb + cc][R0 + r]) + EPS);
        }
        __syncthreads();
    }
    dsum[tq][jc] = csacc;
    __syncthreads();
    if (tid < N)
        dsum[0][tid] = dsum[0][tid] + dsum[1][tid] + dsum[2][tid] + dsum[3][tid];
    __syncthreads();
    // diag override: M[i][i] = colsum_i (i>0)
    if (ty < 16) {
#pragma unroll
        for (int r = 0; r < 8; ++r) {
            const int i = R0 + r;
            if (tx == ((ty << 1) + (r >> 2)) && i != 0)
                m[r][r & 3] =
                    (float)(dsum[0][i] - (double)sdx[i] + 255.0 * (double)EPS);
        }
    } else {
#pragma unroll
        for (int r = 0; r < 8; ++r) {
            const int i = R0 + r;
            if (tx == (((ty - 16) << 1) + (r >> 2)))
                m[r][4 + (r & 3)] =
                    (float)(dsum[0][i] - (double)sdx[i] + 255.0 * (double)EPS);
        }
    }
    if (tx == 0) {   // col-0 override: M[i][0] = exp(x[i][i])
#pragma unroll
        for (int r = 0; r < 8; ++r) m[r][0] = sdx[R0 + r];
    }

    // ===================== PHASE 2: blocked GJ (8 steps) =====================
#pragma unroll 1
    for (int kb = 0; kb < NB_; ++kb) {
        const int k0 = kb * BS;
        const bool rowOwner = (ty >> 2) == kb;
        const bool h0piv = (kb < 4) && ((tx >> 3) == kb);
        const bool h1piv = (kb >= 4) && ((tx >> 3) == kb - 4);
        const int lr = (ty & 3) << 3;           // local row base when rowOwner
        const int lc = (tx & 7) << 2;

        // ---- (a) stage panels from registers ----
        if (rowOwner) {
#pragma unroll
            for (int r = 0; r < 8; ++r) {
                *(float4*)&Rf[lr + r][c0a] =
                    make_float4(m[r][0], m[r][1], m[r][2], m[r][3]);
                *(float4*)&Rf[lr + r][c0b] =
                    make_float4(m[r][4], m[r][5], m[r][6], m[r][7]);
            }
        }
        if (h0piv) {
#pragma unroll
            for (int cc = 0; cc < 4; ++cc) {
                *(float4*)&CfT[lc + cc][R0] =
                    make_float4(m[0][cc], m[1][cc], m[2][cc], m[3][cc]);
                *(float4*)&CfT[lc + cc][R0 + 4] =
                    make_float4(m[4][cc], m[5][cc], m[6][cc], m[7][cc]);
            }
        }
        if (h1piv) {
#pragma unroll
            for (int cc = 0; cc < 4; ++cc) {
                *(float4*)&CfT[lc + cc][R0] =
                    make_float4(m[0][4 + cc], m[1][4 + cc], m[2][4 + cc], m[3][4 + cc]);
                *(float4*)&CfT[lc + cc][R0 + 4] =
                    make_float4(m[4][4 + cc], m[5][4 + cc], m[6][4 + cc], m[7][4 + cc]);
            }
        }
        __syncthreads();   // bar1: panels staged

        // ---- (b) wave-0 register-resident fp64 inversion (round-8 proven) ----
        if (tid < 64) {
            const int l = tid;
            const int row = l & 31;
            const int h = l >> 5, hb = h << 5;
            double p[16];
#pragma unroll
            for (int j = 0; j < 16; ++j)
                p[j] = (double)CfT[(h << 4) + j][k0 + row];

#pragma unroll
            for (int k2 = 0; k2 < BS; ++k2) {
                const int hk2 = k2 >> 4, jk2 = k2 & 15;
                const double cand = p[jk2];
                double av = (h == hk2 && row >= k2) ? fabs(cand) : -1.0;
                double vv = cand;
                int idx = row;
#pragma unroll
                for (int off = 1; off < 64; off <<= 1) {
                    const double oav = __shfl_xor(av, off);
                    const double ovv = __shfl_xor(vv, off);
                    const int    oi  = __shfl_xor(idx, off);
                    if (oav > av || (oav == av && oi < idx)) { av = oav; vv = ovv; idx = oi; }
                }
                const double pivinv = 1.0 / vv;
                if (l == 0) indx[k2] = idx;
                const int prt = (row == k2) ? idx : ((row == idx) ? k2 : row);
                const int sl2 = prt + hb;
#pragma unroll
                for (int j = 0; j < 16; ++j) p[j] = __shfl(p[j], sl2);
                const double scol = __shfl(p[jk2], row + (hk2 << 5));
                const int pl = k2 + hb;
                const bool isPivRow = (row == k2);
#pragma unroll
                for (int j = 0; j < 16; ++j) {
                    const double prow = __shfl(p[j], pl);
                    const bool isK2col = (h == hk2) && (j == jk2);
                    const double srw  = isK2col ? pivinv : prow * pivinv;
                    const double base = isK2col ? 0.0 : p[j];
                    p[j] = isPivRow ? srw : fma(-scol, srw, base);
                }
            }
#pragma unroll
            for (int j = 0; j < 16; ++j)
                Pf[row][(h << 4) + j] = (float)p[j];
            if (l < 32) {   // column unscramble (intra-wave, ordered)
#pragma unroll 1
                for (int k2 = BS - 1; k2 >= 0; --k2) {
                    const int pp = indx[k2];
                    if (pp != k2) {
                        const float t = Pf[l][k2];
                        Pf[l][k2] = Pf[l][pp];
                        Pf[l][pp] = t;
                    }
                }
            }
        }
        __syncthreads();   // bar2: Pf ready

        // ---- (c) R' = P * Rold (fp32); pivot cols <- P; Rf <- R' ----
        {
            float a0[8];
#pragma unroll
            for (int c = 0; c < 8; ++c) a0[c] = 0.f;
#pragma unroll 2
            for (int mm = 0; mm < BS; ++mm) {
                const float p0 = Pf[ty][mm];
                const float4 r0 = *(const float4*)&Rf[mm][c0a];
                const float4 r1 = *(const float4*)&Rf[mm][c0b];
                a0[0] = fmaf(p0, r0.x, a0[0]);
                a0[1] = fmaf(p0, r0.y, a0[1]);
                a0[2] = fmaf(p0, r0.z, a0[2]);
                a0[3] = fmaf(p0, r0.w, a0[3]);
                a0[4] = fmaf(p0, r1.x, a0[4]);
                a0[5] = fmaf(p0, r1.y, a0[5]);
                a0[6] = fmaf(p0, r1.z, a0[6]);
                a0[7] = fmaf(p0, r1.w, a0[7]);
            }
            if (h0piv) {
#pragma unroll
                for (int cc = 0; cc < 4; ++cc) a0[cc] = Pf[ty][lc + cc];
            }
            if (h1piv) {
#pragma unroll
                for (int cc = 0; cc < 4; ++cc) a0[4 + cc] = Pf[ty][lc + cc];
            }
            __syncthreads();   // all reads of Rf(old) complete
            *(float4*)&Rf[ty][c0a] = make_float4(a0[0], a0[1], a0[2], a0[3]);
            *(float4*)&Rf[ty][c0b] = make_float4(a0[4], a0[5], a0[6], a0[7]);
        }
        __syncthreads();   // bar3: R' ready

        // ---- (d) tile update ----
        if (rowOwner) {
#pragma unroll
            for (int r = 0; r < 8; ++r) {
                const float4 b0 = *(const float4*)&Rf[lr + r][c0a];
                const float4 b1 = *(const float4*)&Rf[lr + r][c0b];
                m[r][0] = b0.x; m[r][1] = b0.y; m[r][2] = b0.z; m[r][3] = b0.w;
                m[r][4] = b1.x; m[r][5] = b1.y; m[r][6] = b1.z; m[r][7] = b1.w;
            }
        } else {
            if (h0piv) {
#pragma unroll
                for (int r = 0; r < 8; ++r) {
                    m[r][0] = 0.f; m[r][1] = 0.f; m[r][2] = 0.f; m[r][3] = 0.f;
                }
            }
            if (h1piv) {
#pragma unroll
                for (int r = 0; r < 8; ++r) {
                    m[r][4] = 0.f; m[r][5] = 0.f; m[r][6] = 0.f; m[r][7] = 0.f;
                }
            }
#pragma unroll 2
            for (int mm = 0; mm < BS; ++mm) {
                const float4 rv0 = *(const float4*)&Rf[mm][c0a];
                const float4 rv1 = *(const float4*)&Rf[mm][c0b];
                const float4 cv0 = *(const float4*)&CfT[mm][R0];
                const float4 cv1 = *(const float4*)&CfT[mm][R0 + 4];
                const float cc8[8] = {cv0.x, cv0.y, cv0.z, cv0.w,
                                      cv1.x, cv1.y, cv1.z, cv1.w};
#pragma unroll
                for (int r = 0; r < 8; ++r) {
                    const float cr = -cc8[r];
                    m[r][0] = fmaf(cr, rv0.x, m[r][0]);
                    m[r][1] = fmaf(cr, rv0.y, m[r][1]);
                    m[r][2] = fmaf(cr, rv0.z, m[r][2]);
                    m[r][3] = fmaf(cr, rv0.w, m[r][3]);
                    m[r][4] = fmaf(cr, rv1.x, m[r][4]);
                    m[r][5] = fmaf(cr, rv1.y, m[r][5]);
                    m[r][6] = fmaf(cr, rv1.z, m[r][6]);
                    m[r][7] = fmaf(cr, rv1.w, m[r][7]);
                }
            }
        }
        __syncthreads();   // bar4: Rf/CfT free for next step
    }

    // ===================== PHASE 3: epilogue =====================
    if (ty < 16) {
#pragma unroll
        for (int r = 0; r < 8; ++r) {
            const int i = R0 + r;
            if (tx == ((ty << 1) + (r >> 2))) sdiag_f[i] = m[r][r & 3];
        }
    } else {
#pragma unroll
        for (int r = 0; r < 8; ++r) {
            const int i = R0 + r;
            if (tx == (((ty - 16) << 1) + (r >> 2))) sdiag_f[i] = m[r][4 + (r & 3)];
        }
    }
    if (ty == 0) {
        *(float4*)&sroot_f[c0a] = make_float4(m[0][0], m[0][1], m[0][2], m[0][3]);
        *(float4*)&sroot_f[c0b] = make_float4(m[0][4], m[0][5], m[0][6], m[0][7]);
    }
    __syncthreads();

#pragma unroll
    for (int r = 0; r < 8; ++r) {
        const int a = R0 + r;
        const float rt = sroot_f[a];
        {   // first column group (register diet: one float4 live at a time)
            const float4 x0 = *(const float4*)&xb[(size_t)a * N + c0a];
            float ov[4];
#pragma unroll
            for (int c = 0; c < 4; ++c) {
                const int b_ = c0a + c;
                const float e = expf((c == 0) ? x0.x : (c == 1) ? x0.y
                                    : (c == 2) ? x0.z : x0.w);
                float o = (b_ == 0) ? 0.0f : e * sdiag_f[b_];
                if (a != 0) o -= e * m[r][c];
                if (a == b_) o += e * rt;
                ov[c] = o;
            }
            *(float4*)&ob[(size_t)a * N + c0a] = make_float4(ov[0], ov[1], ov[2], ov[3]);
        }
        {   // second column group
            const float4 x1 = *(const float4*)&xb[(size_t)a * N + c0b];
            float ov[4];
#pragma unroll
            for (int c = 0; c < 4; ++c) {
                const int b_ = c0b + c;
                const float e = expf((c == 0) ? x1.x : (c == 1) ? x1.y
                                    : (c == 2) ? x1.z : x1.w);
                float o = e * sdiag_f[b_];          // b_ >= 128, never col 0
                if (a != 0) o -= e * m[r][4 + c];
                if (a == b_) o += e * rt;
                ov[c] = o;
            }
            *(float4*)&ob[(size_t)a * N + c0b] = make_float4(ov[0], ov[1], ov[2], ov[3]);
        }
    }
}

extern "C" void kernel_launch(void* const* d_in, const int* in_sizes, int n_in,
                              void* d_out, int out_size, void* d_ws, size_t ws_size,
                              hipStream_t stream) {
    const float* x = (const float*)d_in[0];
    float* out = (float*)d_out;
    mtt_fused<<<256, 1024, 0, stream>>>(x, out);
}

// Round 13
// 459.572 us; speedup vs baseline: 1.1082x; 1.1082x over previous
//
#include <hip/hip_runtime.h>
#include <math.h>

#define N 256
#define BS 32
#define NB_ 8
#define EPS 1e-5f

// One block per batch, 1024 threads (16 waves/CU). Thread (ty,tx)=(tid>>5,tid&31)
// owns an 8x8 tile of M = L^T: rows [8ty,8ty+8), cols {4tx..+3} u {128+4tx..+3}.
// vs round 12 (passed, but spilled: VGPR=64 + 350MB scratch traffic): wave-0
// PARKS m[8][8] in LDS across the fp64 register inversion (asm memory clobber
// blocks store-forwarding), so the inversion's p[16] (32 VGPRs) never stacks
// on top of live m -> peak pressure ~95 regs < 128 cap -> no spill.
__global__ __launch_bounds__(1024, 4) void mtt_fused(const float* __restrict__ x,
                                                     float* __restrict__ out) {
    constexpr int LDR = N + 8;
    __shared__ alignas(16) float  Rf[BS][LDR];     // row panel / x strip  33.8KB
    __shared__ alignas(16) float  CfT[BS][LDR];    // col panel, transposed 33.8KB
    __shared__ alignas(16) float  Mpark[64][68];   // wave-0 m parking      17KB
    __shared__ float  Pf[BS][BS + 1];              // inverted pivot fp32   4.2KB
    __shared__ double dsum[4][N];                  // colsum partials       8KB
    __shared__ float  sdx[N];                      // exp(x[i][i])          1KB
    __shared__ float  sdiag_f[N];
    __shared__ float  sroot_f[N];
    __shared__ int    indx[BS];

    const int tid = threadIdx.x;
    const int ty = tid >> 5, tx = tid & 31;        // ty 0..31
    const int R0  = ty << 3;
    const int c0a = tx << 2;
    const int c0b = 128 + (tx << 2);
    const float* xb = x + (size_t)blockIdx.x * N * N;
    float* ob = out + (size_t)blockIdx.x * N * N;

    float m[8][8];

    // ===================== PHASE 1: build M = L^T =====================
    double csacc = 0.0;
    const int tq = tid >> 8, jc = tid & 255;
#pragma unroll 1
    for (int s = 0; s < 8; ++s) {
        {   // coalesced strip load: x rows [32s,32s+32) -> Rf
            const int rl = tid >> 5, cl = (tid & 31) << 3;
            const float* src = &xb[(size_t)(32 * s + rl) * N + cl];
            *(float4*)&Rf[rl][cl]     = *(const float4*)&src[0];
            *(float4*)&Rf[rl][cl + 4] = *(const float4*)&src[4];
        }
        __syncthreads();
#pragma unroll
        for (int r = 0; r < 8; ++r)
            csacc += (double)expf(Rf[(tq << 3) + r][jc]);
        if (tid < 32) sdx[32 * s + tid] = expf(Rf[tid][32 * s + tid]);
        if ((tx >> 3) == s) {               // first-half cols: strips 0-3
            const int jb = (tx & 7) << 2;
#pragma unroll
            for (int cc = 0; cc < 4; ++cc)
#pragma unroll
                for (int r = 0; r < 8; ++r)
                    m[r][cc] = -(expf(Rf[jb + cc][R0 + r]) + EPS);
        }
        if (s >= 4 && (tx >> 3) == s - 4) { // second-half cols: strips 4-7
            const int jb = (tx & 7) << 2;
#pragma unroll
            for (int cc = 0; cc < 4; ++cc)
#pragma unroll
                for (int r = 0; r < 8; ++r)
                    m[r][4 + cc] = -(expf(Rf[jb + cc][R0 + r]) + EPS);
        }
        __syncthreads();
    }
    dsum[tq][jc] = csacc;
    __syncthreads();
    if (tid < N)
        dsum[0][tid] = dsum[0][tid] + dsum[1][tid] + dsum[2][tid] + dsum[3][tid];
    __syncthreads();
    // diag override: M[i][i] = colsum_i (i>0)
    if (ty < 16) {
#pragma unroll
        for (int r = 0; r < 8; ++r) {
            const int i = R0 + r;
            if (tx == ((ty << 1) + (r >> 2)) && i != 0)
                m[r][r & 3] =
                    (float)(dsum[0][i] - (double)sdx[i] + 255.0 * (double)EPS);
        }
    } else {
#pragma unroll
        for (int r = 0; r < 8; ++r) {
            const int i = R0 + r;
            if (tx == (((ty - 16) << 1) + (r >> 2)))
                m[r][4 + (r & 3)] =
                    (float)(dsum[0][i] - (double)sdx[i] + 255.0 * (double)EPS);
        }
    }
    if (tx == 0) {   // col-0 override: M[i][0] = exp(x[i][i])
#pragma unroll
        for (int r = 0; r < 8; ++r) m[r][0] = sdx[R0 + r];
    }

    // ===================== PHASE 2: blocked GJ (8 steps) =====================
#pragma unroll 1
    for (int kb = 0; kb < NB_; ++kb) {
        const int k0 = kb * BS;
        const bool rowOwner = (ty >> 2) == kb;
        const bool h0piv = (kb < 4) && ((tx >> 3) == kb);
        const bool h1piv = (kb >= 4) && ((tx >> 3) == kb - 4);
        const int lr = (ty & 3) << 3;           // local row base when rowOwner
        const int lc = (tx & 7) << 2;

        // ---- (a) stage panels from registers ----
        if (rowOwner) {
#pragma unroll
            for (int r = 0; r < 8; ++r) {
                *(float4*)&Rf[lr + r][c0a] =
                    make_float4(m[r][0], m[r][1], m[r][2], m[r][3]);
                *(float4*)&Rf[lr + r][c0b] =
                    make_float4(m[r][4], m[r][5], m[r][6], m[r][7]);
            }
        }
        if (h0piv) {
#pragma unroll
            for (int cc = 0; cc < 4; ++cc) {
                *(float4*)&CfT[lc + cc][R0] =
                    make_float4(m[0][cc], m[1][cc], m[2][cc], m[3][cc]);
                *(float4*)&CfT[lc + cc][R0 + 4] =
                    make_float4(m[4][cc], m[5][cc], m[6][cc], m[7][cc]);
            }
        }
        if (h1piv) {
#pragma unroll
            for (int cc = 0; cc < 4; ++cc) {
                *(float4*)&CfT[lc + cc][R0] =
                    make_float4(m[0][4 + cc], m[1][4 + cc], m[2][4 + cc], m[3][4 + cc]);
                *(float4*)&CfT[lc + cc][R0 + 4] =
                    make_float4(m[4][4 + cc], m[5][4 + cc], m[6][4 + cc], m[7][4 + cc]);
            }
        }
        __syncthreads();   // bar1: panels staged

        // ---- (b) wave-0: PARK m -> register fp64 inversion -> UNPARK ----
        if (tid < 64) {
            // park m in LDS to break its live range across the inversion
#pragma unroll
            for (int r = 0; r < 8; ++r) {
                *(float4*)&Mpark[tid][r << 3] =
                    make_float4(m[r][0], m[r][1], m[r][2], m[r][3]);
                *(float4*)&Mpark[tid][(r << 3) + 4] =
                    make_float4(m[r][4], m[r][5], m[r][6], m[r][7]);
            }
            asm volatile("" ::: "memory");   // no store-forwarding: m regs freed

            const int l = tid;
            const int row = l & 31;
            const int h = l >> 5, hb = h << 5;
            double p[16];
#pragma unroll
            for (int j = 0; j < 16; ++j)
                p[j] = (double)CfT[(h << 4) + j][k0 + row];

#pragma unroll
            for (int k2 = 0; k2 < BS; ++k2) {
                const int hk2 = k2 >> 4, jk2 = k2 & 15;
                const double cand = p[jk2];
                double av = (h == hk2 && row >= k2) ? fabs(cand) : -1.0;
                double vv = cand;
                int idx = row;
#pragma unroll
                for (int off = 1; off < 64; off <<= 1) {
                    const double oav = __shfl_xor(av, off);
                    const double ovv = __shfl_xor(vv, off);
                    const int    oi  = __shfl_xor(idx, off);
                    if (oav > av || (oav == av && oi < idx)) { av = oav; vv = ovv; idx = oi; }
                }
                const double pivinv = 1.0 / vv;
                if (l == 0) indx[k2] = idx;
                const int prt = (row == k2) ? idx : ((row == idx) ? k2 : row);
                const int sl2 = prt + hb;
#pragma unroll
                for (int j = 0; j < 16; ++j) p[j] = __shfl(p[j], sl2);
                const double scol = __shfl(p[jk2], row + (hk2 << 5));
                const int pl = k2 + hb;
                const bool isPivRow = (row == k2);
#pragma unroll
                for (int j = 0; j < 16; ++j) {
                    const double prow = __shfl(p[j], pl);
                    const bool isK2col = (h == hk2) && (j == jk2);
                    const double srw  = isK2col ? pivinv : prow * pivinv;
                    const double base = isK2col ? 0.0 : p[j];
                    p[j] = isPivRow ? srw : fma(-scol, srw, base);
                }
            }
#pragma unroll
            for (int j = 0; j < 16; ++j)
                Pf[row][(h << 4) + j] = (float)p[j];
            if (l < 32) {   // column unscramble (intra-wave, ordered)
#pragma unroll 1
                for (int k2 = BS - 1; k2 >= 0; --k2) {
                    const int pp = indx[k2];
                    if (pp != k2) {
                        const float t = Pf[l][k2];
                        Pf[l][k2] = Pf[l][pp];
                        Pf[l][pp] = t;
                    }
                }
            }

            asm volatile("" ::: "memory");   // force true reload of m
            // unpark
#pragma unroll
            for (int r = 0; r < 8; ++r) {
                const float4 q0 = *(const float4*)&Mpark[tid][r << 3];
                const float4 q1 = *(const float4*)&Mpark[tid][(r << 3) + 4];
                m[r][0] = q0.x; m[r][1] = q0.y; m[r][2] = q0.z; m[r][3] = q0.w;
                m[r][4] = q1.x; m[r][5] = q1.y; m[r][6] = q1.z; m[r][7] = q1.w;
            }
        }
        __syncthreads();   // bar2: Pf ready

        // ---- (c) R' = P * Rold (fp32); pivot cols <- P; Rf <- R' ----
        {
            float a0[8];
#pragma unroll
            for (int c = 0; c < 8; ++c) a0[c] = 0.f;
#pragma unroll 2
            for (int mm = 0; mm < BS; ++mm) {
                const float p0 = Pf[ty][mm];
                const float4 r0 = *(const float4*)&Rf[mm][c0a];
                const float4 r1 = *(const float4*)&Rf[mm][c0b];
                a0[0] = fmaf(p0, r0.x, a0[0]);
                a0[1] = fmaf(p0, r0.y, a0[1]);
                a0[2] = fmaf(p0, r0.z, a0[2]);
                a0[3] = fmaf(p0, r0.w, a0[3]);
                a0[4] = fmaf(p0, r1.x, a0[4]);
                a0[5] = fmaf(p0, r1.y, a0[5]);
                a0[6] = fmaf(p0, r1.z, a0[6]);
                a0[7] = fmaf(p0, r1.w, a0[7]);
            }
            if (h0piv) {
#pragma unroll
                for (int cc = 0; cc < 4; ++cc) a0[cc] = Pf[ty][lc + cc];
            }
            if (h1piv) {
#pragma unroll
                for (int cc = 0; cc < 4; ++cc) a0[4 + cc] = Pf[ty][lc + cc];
            }
            __syncthreads();   // all reads of Rf(old) complete
            *(float4*)&Rf[ty][c0a] = make_float4(a0[0], a0[1], a0[2], a0[3]);
            *(float4*)&Rf[ty][c0b] = make_float4(a0[4], a0[5], a0[6], a0[7]);
        }
        __syncthreads();   // bar3: R' ready

        // ---- (d) tile update ----
        if (rowOwner) {
#pragma unroll
            for (int r = 0; r < 8; ++r) {
                const float4 b0 = *(const float4*)&Rf[lr + r][c0a];
                const float4 b1 = *(const float4*)&Rf[lr + r][c0b];
                m[r][0] = b0.x; m[r][1] = b0.y; m[r][2] = b0.z; m[r][3] = b0.w;
                m[r][4] = b1.x; m[r][5] = b1.y; m[r][6] = b1.z; m[r][7] = b1.w;
            }
        } else {
            if (h0piv) {
#pragma unroll
                for (int r = 0; r < 8; ++r) {
                    m[r][0] = 0.f; m[r][1] = 0.f; m[r][2] = 0.f; m[r][3] = 0.f;
                }
            }
            if (h1piv) {
#pragma unroll
                for (int r = 0; r < 8; ++r) {
                    m[r][4] = 0.f; m[r][5] = 0.f; m[r][6] = 0.f; m[r][7] = 0.f;
                }
            }
#pragma unroll 2
            for (int mm = 0; mm < BS; ++mm) {
                const float4 rv0 = *(const float4*)&Rf[mm][c0a];
                const float4 rv1 = *(const float4*)&Rf[mm][c0b];
                const float4 cv0 = *(const float4*)&CfT[mm][R0];
                const float4 cv1 = *(const float4*)&CfT[mm][R0 + 4];
                const float cc8[8] = {cv0.x, cv0.y, cv0.z, cv0.w,
                                      cv1.x, cv1.y, cv1.z, cv1.w};
#pragma unroll
                for (int r = 0; r < 8; ++r) {
                    const float cr = -cc8[r];
                    m[r][0] = fmaf(cr, rv0.x, m[r][0]);
                    m[r][1] = fmaf(cr, rv0.y, m[r][1]);
                    m[r][2] = fmaf(cr, rv0.z, m[r][2]);
                    m[r][3] = fmaf(cr, rv0.w, m[r][3]);
                    m[r][4] = fmaf(cr, rv1.x, m[r][4]);
                    m[r][5] = fmaf(cr, rv1.y, m[r][5]);
                    m[r][6] = fmaf(cr, rv1.z, m[r][6]);
                    m[r][7] = fmaf(cr, rv1.w, m[r][7]);
                }
            }
        }
        __syncthreads();   // bar4: Rf/CfT free for next step
    }

    // ===================== PHASE 3: epilogue =====================
    if (ty < 16) {
#pragma unroll
        for (int r = 0; r < 8; ++r) {
            const int i = R0 + r;
            if (tx == ((ty << 1) + (r >> 2))) sdiag_f[i] = m[r][r & 3];
        }
    } else {
#pragma unroll
        for (int r = 0; r < 8; ++r) {
            const int i = R0 + r;
            if (tx == (((ty - 16) << 1) + (r >> 2))) sdiag_f[i] = m[r][4 + (r & 3)];
        }
    }
    if (ty == 0) {
        *(float4*)&sroot_f[c0a] = make_float4(m[0][0], m[0][1], m[0][2], m[0][3]);
        *(float4*)&sroot_f[c0b] = make_float4(m[0][4], m[0][5], m[0][6], m[0][7]);
    }
    __syncthreads();

#pragma unroll
    for (int r = 0; r < 8; ++r) {
        const int a = R0 + r;
        const float rt = sroot_f[a];
        {   // first column group (register diet: one float4 live at a time)
            const float4 x0 = *(const float4*)&xb[(size_t)a * N + c0a];
            float ov[4];
#pragma unroll
            for (int c = 0; c < 4; ++c) {
                const int b_ = c0a + c;
                const float e = expf((c == 0) ? x0.x : (c == 1) ? x0.y
                                    : (c == 2) ? x0.z : x0.w);
                float o = (b_ == 0) ? 0.0f : e * sdiag_f[b_];
                if (a != 0) o -= e * m[r][c];
                if (a == b_) o += e * rt;
                ov[c] = o;
            }
            *(float4*)&ob[(size_t)a * N + c0a] = make_float4(ov[0], ov[1], ov[2], ov[3]);
        }
        {   // second column group
            const float4 x1 = *(const float4*)&xb[(size_t)a * N + c0b];
            float ov[4];
#pragma unroll
            for (int c = 0; c < 4; ++c) {
                const int b_ = c0b + c;
                const float e = expf((c == 0) ? x1.x : (c == 1) ? x1.y
                                    : (c == 2) ? x1.z : x1.w);
                float o = e * sdiag_f[b_];          // b_ >= 128, never col 0
                if (a != 0) o -= e * m[r][4 + c];
                if (a == b_) o += e * rt;
                ov[c] = o;
            }
            *(float4*)&ob[(size_t)a * N + c0b] = make_float4(ov[0], ov[1], ov[2], ov[3]);
        }
    }
}

extern "C" void kernel_launch(void* const* d_in, const int* in_sizes, int n_in,
                              void* d_out, int out_size, void* d_ws, size_t ws_size,
                              hipStream_t stream) {
    const float* x = (const float*)d_in[0];
    float* out = (float*)d_out;
    mtt_fused<<<256, 1024, 0, stream>>>(x, out);
}